// Round 5
// baseline (93.393 us; speedup 1.0000x reference)
//
#include <hip/hip_runtime.h>
#include <math.h>

// RESUS_NN_2327872274812: Q=8192, S=30, D=512.  FP32-exact, deterministic.
// r19 = r18 + double-buffered sp: stage chunk p+1 CONCURRENT with reduce p.
// History: r14 93.3 | r15 2q/thr 94.4 | r16 A-misplaced 94.0 | r17 A+reg-
// prefetch 98.4 (VGPR cap 128 blown -> spills) | r18 A-isolated 92.9 (best).
// r18 post-mortem: q-burst overlap recovered only 0.33us (cross-wave TLP
// already hid most of it). Remaining structure cost: 2 standalone staging
// phases (barrier+load+scat+barrier) and 3 reduce phases where 352/512
// threads idle. Fix: sp[2]; during reduce p (tid<160, 2.5 waves), threads
// tid>=192 (5 waves) load chunk p+1 and scat into the OTHER sp buffer.
// Deletes 2 barriers + 2 staging spans. Staging temps are transient
// post-hot (accumulators dead) -> no VGPR pressure (r17's trap avoided).
// All accumulation orders r18-identical -> absmax 0.0 preserved.
// LDS: 2*23,200 + 21,760 + 3,968 = 72,128 B < 80 KB -> 2 blocks/CU kept.
// thread = (ql 0..15, dseg 0..15, shalf 0..1): query ql, 32-float d-slice,
// 5 support rows per pass (shalf picks which half of the 10-row chunk).

#define QN 8192
#define SN 30
#define DN 512
#define BLK 512
#define QT 16            // queries per block
#define SCHUNK 10        // support rows per pass
#define NPASS 3
#define SROW 580         // floats per LDS support row (16 segs * 36 + 4)
#define PRW 17           // praw ql-dim stride (floats)
#define PSTR 31          // final part row stride (float2)

__global__ __launch_bounds__(BLK, 2)
void resus_one(const float* __restrict__ query,      // [Q][D]
               const float* __restrict__ support,    // [S][D]
               const float* __restrict__ support_y,  // [S]
               const float* __restrict__ support_pr, // [S]
               const float* __restrict__ query_pr,   // [Q]
               const float* __restrict__ fc1_w,      // [D]
               const float* __restrict__ adj_scale,  // [30]
               const float* __restrict__ adj_bias,   // [30]
               const int*   __restrict__ num_samples,// [1]
               float* __restrict__ out)              // [2*Q]
{
    __shared__ float  sp[2][SCHUNK * SROW];       // 46,400 B (double buffer)
    __shared__ float  praw_sc[SCHUNK * QT * PRW]; // 10,880 B
    __shared__ float  praw_sq[SCHUNK * QT * PRW]; // 10,880 B
    __shared__ float2 part[QT * PSTR];            //  3,968 B  total 72,128 B

    const int tid   = threadIdx.x;
    const int ql    = tid & 15;               // query slot (lane-fast)
    const int dseg  = (tid >> 4) & 15;        // 32-float d-segment
    const int shalf = tid >> 8;               // 0/1: which 5 rows of a chunk
    const int q     = blockIdx.x * QT + ql;
    const bool has2 = (tid < 256);            // 1280 - 1024 float4s

    // scatter: i-th float4 of a chunk -> segmented slot in buffer BUF
#define SCAT(BUF, V, I) { const int i_ = (I), row_ = i_ >> 7, c4_ = i_ & 127; \
    *reinterpret_cast<float4*>((BUF) + row_ * SROW + 36 * (c4_ >> 3) + 4 * (c4_ & 7)) = (V); }

    // ---- stage chunk 0 -> sp[0] (only these loads outstanding at bar) ----
    {
        const float4* sg0 = reinterpret_cast<const float4*>(support);
        float4 g0 = sg0[tid];                 // SCHUNK*128 = 1280 float4s
        float4 g1 = sg0[tid + 512];
        float4 g2;
        if (has2) g2 = sg0[tid + 1024];
        SCAT(sp[0], g0, tid)
        SCAT(sp[0], g1, tid + 512)
        if (has2) SCAT(sp[0], g2, tid + 1024)
    }
    __syncthreads();
    // anti-hoist fence: q/w loads must NOT migrate above the barrier, or
    // its vmcnt(0) drain serializes the whole query burst (r16's failure).
    asm volatile("" ::: "memory");

    // ---- q + w slices, per-subsegment interleaved issue order ----
    const float* qp = query + (size_t)q * DN + dseg * 32;
    const float* wp = fc1_w + dseg * 32;
    float4 a0 = *reinterpret_cast<const float4*>(qp +  0);
    float4 w0 = *reinterpret_cast<const float4*>(wp +  0);
    float4 a1 = *reinterpret_cast<const float4*>(qp +  4);
    float4 w1 = *reinterpret_cast<const float4*>(wp +  4);
    float4 a2 = *reinterpret_cast<const float4*>(qp +  8);
    float4 w2 = *reinterpret_cast<const float4*>(wp +  8);
    float4 a3 = *reinterpret_cast<const float4*>(qp + 12);
    float4 w3 = *reinterpret_cast<const float4*>(wp + 12);
    float4 a4 = *reinterpret_cast<const float4*>(qp + 16);
    float4 w4 = *reinterpret_cast<const float4*>(wp + 16);
    float4 a5 = *reinterpret_cast<const float4*>(qp + 20);
    float4 w5 = *reinterpret_cast<const float4*>(wp + 20);
    float4 a6 = *reinterpret_cast<const float4*>(qp + 24);
    float4 w6 = *reinterpret_cast<const float4*>(wp + 24);
    float4 a7 = *reinterpret_cast<const float4*>(qp + 28);
    float4 w7 = *reinterpret_cast<const float4*>(wp + 28);

    // per-component chain: sub, fma(w,|d|,sc), fma(d,d,sq), d-ascending --
    // identical rounding to r14/r18 for every (q, row).
#define ACCD(QV, WV, SV, SC, SQ) { float d_; \
    d_ = (QV).x - (SV).x; SC = fmaf((WV).x, fabsf(d_), SC); SQ = fmaf(d_, d_, SQ); \
    d_ = (QV).y - (SV).y; SC = fmaf((WV).y, fabsf(d_), SC); SQ = fmaf(d_, d_, SQ); \
    d_ = (QV).z - (SV).z; SC = fmaf((WV).z, fabsf(d_), SC); SQ = fmaf(d_, d_, SQ); \
    d_ = (QV).w - (SV).w; SC = fmaf((WV).w, fabsf(d_), SC); SQ = fmaf(d_, d_, SQ); }

    const int sbase = dseg * 36;
    const int pbase = ql * PRW + dseg;        // praw offset (sl adds QT*PRW)
    const int sl0   = shalf * (SCHUNK / 2);   // 0 or 5

    // ---- pass 0: subseg-outer / row-inner; step j waits only a_j/w_j ----
    {
        const float* r0 = sp[0] + (sl0 + 0) * SROW + sbase;
        const float* r1 = sp[0] + (sl0 + 1) * SROW + sbase;
        const float* r2 = sp[0] + (sl0 + 2) * SROW + sbase;
        const float* r3 = sp[0] + (sl0 + 3) * SROW + sbase;
        const float* r4 = sp[0] + (sl0 + 4) * SROW + sbase;
        float sc0 = 0.0f, sc1 = 0.0f, sc2 = 0.0f, sc3 = 0.0f, sc4 = 0.0f;
        float sq0 = 0.0f, sq1 = 0.0f, sq2 = 0.0f, sq3 = 0.0f, sq4 = 0.0f;

#define SEG0(AJ, WJ, OFF) { float4 s_; \
    s_ = *reinterpret_cast<const float4*>(r0 + (OFF)); ACCD(AJ, WJ, s_, sc0, sq0); \
    s_ = *reinterpret_cast<const float4*>(r1 + (OFF)); ACCD(AJ, WJ, s_, sc1, sq1); \
    s_ = *reinterpret_cast<const float4*>(r2 + (OFF)); ACCD(AJ, WJ, s_, sc2, sq2); \
    s_ = *reinterpret_cast<const float4*>(r3 + (OFF)); ACCD(AJ, WJ, s_, sc3, sq3); \
    s_ = *reinterpret_cast<const float4*>(r4 + (OFF)); ACCD(AJ, WJ, s_, sc4, sq4); }

        SEG0(a0, w0,  0) SEG0(a1, w1,  4) SEG0(a2, w2,  8) SEG0(a3, w3, 12)
        SEG0(a4, w4, 16) SEG0(a5, w5, 20) SEG0(a6, w6, 24) SEG0(a7, w7, 28)
#undef SEG0

        praw_sc[(sl0 + 0) * (QT * PRW) + pbase] = sc0;
        praw_sq[(sl0 + 0) * (QT * PRW) + pbase] = sq0;
        praw_sc[(sl0 + 1) * (QT * PRW) + pbase] = sc1;
        praw_sq[(sl0 + 1) * (QT * PRW) + pbase] = sq1;
        praw_sc[(sl0 + 2) * (QT * PRW) + pbase] = sc2;
        praw_sq[(sl0 + 2) * (QT * PRW) + pbase] = sq2;
        praw_sc[(sl0 + 3) * (QT * PRW) + pbase] = sc3;
        praw_sq[(sl0 + 3) * (QT * PRW) + pbase] = sq3;
        praw_sc[(sl0 + 4) * (QT * PRW) + pbase] = sc4;
        praw_sq[(sl0 + 4) * (QT * PRW) + pbase] = sq4;
    }

    // ---- pin q/w for passes 1-2 (r11-proven; after pass 0 so it never
    //      forces an early vmcnt drain) ----
#define PIN4(V) asm volatile("" : "+v"((V).x), "+v"((V).y), "+v"((V).z), "+v"((V).w))
    PIN4(a0); PIN4(a1); PIN4(a2); PIN4(a3);
    PIN4(a4); PIN4(a5); PIN4(a6); PIN4(a7);
    PIN4(w0); PIN4(w1); PIN4(w2); PIN4(w3);
    PIN4(w4); PIN4(w5); PIN4(w6); PIN4(w7);
#undef PIN4

    // ---- reduce over dseg (fixed ascending order), r18-identical ----
#define REDUCE(POFF) \
    { const int sl_ = tid >> 4, qq_ = tid & 15; \
      const int b_ = sl_ * (QT * PRW) + qq_ * PRW; \
      float sc_ = 0.0f, sq_ = 0.0f; \
      _Pragma("unroll") \
      for (int d = 0; d < 16; ++d) { \
          sc_ += praw_sc[b_ + d]; \
          sq_ += praw_sq[b_ + d]; \
      } \
      part[qq_ * PSTR + (POFF) + sl_] = make_float2(sc_, sq_); }

    // fused staging: 320 threads (tid>=192) load chunk CH -> buffer BUF
#define STAGEF(BUF, CH) \
    { const float4* sg_ = reinterpret_cast<const float4*>( \
          support + (size_t)(CH) * SCHUNK * DN); \
      const int j_ = tid - 192; \
      float4 g0_ = sg_[j_]; \
      float4 g1_ = sg_[j_ + 320]; \
      float4 g2_ = sg_[j_ + 640]; \
      float4 g3_ = sg_[j_ + 960]; \
      SCAT(BUF, g0_, j_) \
      SCAT(BUF, g1_, j_ + 320) \
      SCAT(BUF, g2_, j_ + 640) \
      SCAT(BUF, g3_, j_ + 960) }

    __syncthreads();   // praw writes visible; sp[0] readers done

    // ---- fused: reduce0 (tid<160) || stage chunk1 -> sp[1] (tid>=192) ----
    if (tid < SCHUNK * QT) {
        REDUCE(0)
    } else if (tid >= 192) {
        STAGEF(sp[1], 1)
    }
    __syncthreads();   // part0 + chunk-1 staged

    // hot-loop macro (ambient sc/sq), r14/r18-identical body
#define ACC4(QV, WV, SV) { float d_; \
    d_ = (QV).x - (SV).x; sc = fmaf((WV).x, fabsf(d_), sc); sq = fmaf(d_, d_, sq); \
    d_ = (QV).y - (SV).y; sc = fmaf((WV).y, fabsf(d_), sc); sq = fmaf(d_, d_, sq); \
    d_ = (QV).z - (SV).z; sc = fmaf((WV).z, fabsf(d_), sc); sq = fmaf(d_, d_, sq); \
    d_ = (QV).w - (SV).w; sc = fmaf((WV).w, fabsf(d_), sc); sq = fmaf(d_, d_, sq); }

#define HOTPASS(BUF) \
    _Pragma("unroll") \
    for (int k = 0; k < SCHUNK / 2; ++k) { \
        const int sl = sl0 + k; \
        const float* sr = (BUF) + sl * SROW + sbase; \
        const float4 s0 = *reinterpret_cast<const float4*>(sr +  0); \
        const float4 s1 = *reinterpret_cast<const float4*>(sr +  4); \
        const float4 s2 = *reinterpret_cast<const float4*>(sr +  8); \
        const float4 s3 = *reinterpret_cast<const float4*>(sr + 12); \
        const float4 s4 = *reinterpret_cast<const float4*>(sr + 16); \
        const float4 s5 = *reinterpret_cast<const float4*>(sr + 20); \
        const float4 s6 = *reinterpret_cast<const float4*>(sr + 24); \
        const float4 s7 = *reinterpret_cast<const float4*>(sr + 28); \
        float sc = 0.0f, sq = 0.0f; \
        ACC4(a0, w0, s0) ACC4(a1, w1, s1) \
        ACC4(a2, w2, s2) ACC4(a3, w3, s3) \
        ACC4(a4, w4, s4) ACC4(a5, w5, s5) \
        ACC4(a6, w6, s6) ACC4(a7, w7, s7) \
        praw_sc[sl * (QT * PRW) + pbase] = sc; \
        praw_sq[sl * (QT * PRW) + pbase] = sq; \
    }

    // ---- pass 1 hot (reads sp[1]) ----
    HOTPASS(sp[1])
    __syncthreads();   // praw visible; sp[1] readers done

    // ---- fused: reduce1 || stage chunk2 -> sp[0] (sp[0] idle since p0) ----
    if (tid < SCHUNK * QT) {
        REDUCE(SCHUNK)
    } else if (tid >= 192) {
        STAGEF(sp[0], 2)
    }
    __syncthreads();   // part1 + chunk-2 staged

    // ---- pass 2 hot (reads sp[0]) ----
    HOTPASS(sp[0])
    __syncthreads();   // praw visible

    // ---- reduce2 (no staging left) ----
    if (tid < SCHUNK * QT) {
        REDUCE(2 * SCHUNK)
    }
#undef HOTPASS
#undef ACC4
#undef STAGEF
#undef REDUCE
#undef ACCD
#undef SCAT
    __syncthreads();   // all part[] writes visible

    // ---- epilogue: 16 half-wave groups; group g = query g (r14) ----
    const int grp  = tid >> 5;                // 0..15
    const int s32  = tid & 31;
    const bool valid = (s32 < SN);
    const int  si  = valid ? s32 : 0;

    float dy = 0.0f;
    if (valid)
        dy = support_y[s32] - 1.0f / (1.0f + expf(-support_pr[s32]));

    const int ns = num_samples[0];
    const float ascale = fabsf(adj_scale[ns - 1]);
    const float abias  = adj_bias[ns - 1];

    const int qg = blockIdx.x * QT + grp;
    const float2 pr = part[grp * PSTR + si];

    float scv = valid ? pr.x : -1e30f;
    float ssv = valid ? pr.y : 0.0f;

    float m = scv;
#pragma unroll
    for (int off = 16; off >= 1; off >>= 1)
        m = fmaxf(m, __shfl_xor(m, off));

    float e   = valid ? expf(scv - m) : 0.0f;
    float den = e;
    float num = dy * e;
    float l2  = valid ? sqrtf(ssv) : 0.0f;
#pragma unroll
    for (int off = 16; off >= 1; off >>= 1) {
        den += __shfl_xor(den, off);
        num += __shfl_xor(num, off);
        l2  += __shfl_xor(l2,  off);
    }

    if (s32 == 0) {
        out[qg]      = num / den * ascale + abias + query_pr[qg];
        out[QN + qg] = l2 * (1.0f / (float)SN);
    }
}

extern "C" void kernel_launch(void* const* d_in, const int* in_sizes, int n_in,
                              void* d_out, int out_size, void* d_ws, size_t ws_size,
                              hipStream_t stream)
{
    const float* query      = (const float*)d_in[0];
    const float* support    = (const float*)d_in[1];
    const float* support_y  = (const float*)d_in[2];
    const float* support_pr = (const float*)d_in[3];
    const float* query_pr   = (const float*)d_in[4];
    const float* fc1_w      = (const float*)d_in[5];
    // d_in[6] = fc1_b: cancels in softmax, unused
    const float* adj_scale  = (const float*)d_in[7];
    const float* adj_bias   = (const float*)d_in[8];
    const int*   num_s      = (const int*)d_in[9];
    float* out = (float*)d_out;

    dim3 grid(QN / QT);      // 512 blocks x 8 waves = 4096 waves = 4/SIMD
    hipLaunchKernelGGL(resus_one, grid, dim3(BLK), 0, stream,
                       query, support, support_y, support_pr, query_pr,
                       fc1_w, adj_scale, adj_bias, num_s, out);
}